// Round 1
// baseline (332.808 us; speedup 1.0000x reference)
//
#include <hip/hip_runtime.h>

#define NB 8
#define NN 20000
#define FI 128
#define FO 128
#define NE 320000
#define ROWS (NB * NN)        // 160000 flattened (b,n) rows
#define LRALPHA 0.2f

typedef short bf16x8 __attribute__((ext_vector_type(8)));
typedef float f32x4 __attribute__((ext_vector_type(4)));

static __device__ __forceinline__ float b2f(unsigned short u) {
  return __uint_as_float(((unsigned int)u) << 16);
}
static __device__ __forceinline__ unsigned short f2b(float f) {
  unsigned int u = __float_as_uint(f);
  return (unsigned short)((u + 0x7FFFu + ((u >> 16) & 1u)) >> 16);  // RNE
}

// ---- W transpose: W[k][o] fp32 -> Wb[o][k] bf16; also zero counts ---------
__global__ __launch_bounds__(256) void wt_kernel(const float* __restrict__ W,
                                                 unsigned short* __restrict__ Wb,
                                                 int* __restrict__ counts) {
  int idx = blockIdx.x * 256 + threadIdx.x;  // 80 blocks -> 20480 threads
  if (idx < FI * FO) {
    int k = idx >> 7, o = idx & 127;
    Wb[o * 128 + k] = f2b(W[idx]);
  }
  if (idx < NN) counts[idx] = 0;
}

// ---- GEMM: Wb read direct from global (L1-resident, 32 KB); no LDS --------
// Removing the LDS staging kills the barrier + the 4-blocks/CU LDS cap.
__global__ __launch_bounds__(256) void gemm_kernel(
    const float* __restrict__ x, const unsigned short* __restrict__ Wb,
    const float* __restrict__ a,
    unsigned short* __restrict__ hb,
    float* __restrict__ g1, float* __restrict__ g2) {
  const int tid = threadIdx.x;
  const int wv = tid >> 6;
  const int lane = tid & 63;
  const int m = lane & 15;
  const int quad = lane >> 4;
  const size_t row0 = (size_t)blockIdx.x * 64 + wv * 16;  // wave's first row

  // A-fragments: x[row0+m][k0*32 + quad*8 .. +8] fp32 -> bf16 in-reg
  const float* xr = x + (row0 + m) * 128;
  bf16x8 afr[4];
#pragma unroll
  for (int k0 = 0; k0 < 4; ++k0) {
    const float4* xp = (const float4*)(xr + k0 * 32 + quad * 8);
    float4 v0 = xp[0];
    float4 v1 = xp[1];
    union { bf16x8 v; unsigned short u[8]; } af;
    af.u[0] = f2b(v0.x); af.u[1] = f2b(v0.y);
    af.u[2] = f2b(v0.z); af.u[3] = f2b(v0.w);
    af.u[4] = f2b(v1.x); af.u[5] = f2b(v1.y);
    af.u[6] = f2b(v1.z); af.u[7] = f2b(v1.w);
    afr[k0] = af.v;
  }

  f32x4 acc[8] = {};
#pragma unroll
  for (int k0 = 0; k0 < 4; ++k0) {
#pragma unroll
    for (int c = 0; c < 8; ++c) {
      bf16x8 bf = *(const bf16x8*)&Wb[(c * 16 + m) * 128 + k0 * 32 + quad * 8];
      acc[c] = __builtin_amdgcn_mfma_f32_16x16x32_bf16(afr[k0], bf, acc[c], 0, 0, 0);
    }
  }

  // C/D layout: col = lane&15 (within c-tile), row = quad*4 + r
  unsigned short* hp = hb + row0 * 128;
#pragma unroll
  for (int c = 0; c < 8; ++c)
#pragma unroll
    for (int r = 0; r < 4; ++r)
      hp[(quad * 4 + r) * 128 + c * 16 + m] = f2b(acc[c][r]);

  // fused g1/g2: per-row dot with a1/a2 from fp32 accumulators
  float a1v[8], a2v[8];
#pragma unroll
  for (int c = 0; c < 8; ++c) {
    a1v[c] = a[c * 16 + m];
    a2v[c] = a[128 + c * 16 + m];
  }
  float p1[4] = {}, p2[4] = {};
#pragma unroll
  for (int c = 0; c < 8; ++c)
#pragma unroll
    for (int r = 0; r < 4; ++r) {
      p1[r] = fmaf(acc[c][r], a1v[c], p1[r]);
      p2[r] = fmaf(acc[c][r], a2v[c], p2[r]);
    }
#pragma unroll
  for (int off = 1; off < 16; off <<= 1)
#pragma unroll
    for (int r = 0; r < 4; ++r) {
      p1[r] += __shfl_xor(p1[r], off, 64);
      p2[r] += __shfl_xor(p2[r], off, 64);
    }
  if (m == 0) {
    size_t rbase = row0 + quad * 4;
#pragma unroll
    for (int r = 0; r < 4; ++r) {
      g1[rbase + r] = p1[r];
      g2[rbase + r] = p2[r];
    }
  }
}

// ---------------- CSR build: histogram -> scan -> scatter -------------------
__global__ __launch_bounds__(256) void hist_kernel(const int* __restrict__ src,
                                                   int* __restrict__ counts) {
  int e = blockIdx.x * 256 + threadIdx.x;
  if (e < NE) atomicAdd(&counts[src[e]], 1);
}

__global__ __launch_bounds__(1024) void scan_kernel(
    const int* __restrict__ counts, int* __restrict__ offsets,
    int* __restrict__ cursor) {
  __shared__ int sc[NN];      // 80 KB
  __shared__ int sums[1024];
  const int t = threadIdx.x;
  for (int idx = t; idx < NN; idx += 1024) sc[idx] = counts[idx];  // coalesced
  __syncthreads();
  int local[20];
  int base = t * 20;
  int s = 0;
#pragma unroll
  for (int c = 0; c < 20; ++c) {
    int idx = base + c;
    int v = (idx < NN) ? sc[idx] : 0;
    local[c] = s;
    s += v;
  }
  sums[t] = s;
  __syncthreads();
  for (int off = 1; off < 1024; off <<= 1) {
    int u = 0;
    if (t >= off) u = sums[t - off];
    __syncthreads();
    sums[t] += u;
    __syncthreads();
  }
  int prefix = sums[t] - s;  // exclusive over threads
#pragma unroll
  for (int c = 0; c < 20; ++c) {
    int idx = base + c;
    if (idx < NN) {
      int o = prefix + local[c];
      offsets[idx] = o;
      cursor[idx] = o;
    }
  }
  if (t == 0) offsets[NN] = NE;
}

// scatter: store dst directly at CSR position
__global__ __launch_bounds__(256) void scatter_kernel(
    const int* __restrict__ src, const int* __restrict__ dst,
    int* __restrict__ cursor, int* __restrict__ csr_dst) {
  int e = blockIdx.x * 256 + threadIdx.x;
  if (e < NE) {
    int s = src[e];
    int d = dst[e];
    int pos = atomicAdd(&cursor[s], 1);
    csr_dst[pos] = d;
  }
}

// ---------------- gather: per (node i, batch b) segment reduce --------------
// XCD-affine: batch = blockIdx.x & 7 so each XCD (round-robin %8 dispatch)
// works on exactly one batch's 5.12 MB hb slice -> L2-resident h-row reuse.
// 4 nodes per 256-thread block (4 independent waves, no barrier) to cut the
// workgroup count 160000 -> 40000.
__global__ __launch_bounds__(256) void gather_kernel(
    const unsigned short* __restrict__ hb, const float* __restrict__ g1,
    const float* __restrict__ g2, const int* __restrict__ offsets,
    const int* __restrict__ csr_dst, float* __restrict__ out) {
  const int bid = blockIdx.x;
  const int b = bid & 7;            // XCD-affine batch
  const int chunk = bid >> 3;
  const int wv = threadIdx.x >> 6;
  const int i = chunk * 4 + wv;     // node handled by this wave
  const int lane = threadIdx.x & 63;
  const int quad = lane >> 4;
  const int beg = offsets[i];
  const int deg = offsets[i + 1] - beg;
  const float g1i = g1[(size_t)b * NN + i];
  const float* g2b = g2 + (size_t)b * NN;
  // lane's 16B slice within any h-row of batch b
  const char* hbase = (const char*)(hb + (size_t)b * NN * 128) + (lane & 15) * 16;

  float acc[8] = {};
  float rs = 0.f;
  for (int c0 = 0; c0 < deg; c0 += 64) {
    const int cnt = min(64, deg - c0);
    // lane-parallel: lane e computes weight for edge beg+c0+e (coalesced idx)
    int myd = 0;
    float w = 0.f;
    if (lane < cnt) {
      myd = csr_dst[beg + c0 + lane];
      float s = g1i + g2b[myd];
      float sc = fmaxf(s, LRALPHA * s);
      w = __expf(-sc);
    }
    rs += w;
    // 4 edges per load: quad q takes edge e+j*4+q; zero-weight padding
    const int cr = (cnt + 15) & ~15;
    for (int e = 0; e < cr; e += 16) {
      bf16x8 hv[4];
      float we[4];
#pragma unroll
      for (int j = 0; j < 4; ++j) {
        int idx = e + j * 4 + quad;
        int d = __shfl(myd, idx, 64);
        we[j] = __shfl(w, idx, 64);
        hv[j] = *(const bf16x8*)(hbase + (d << 8));
      }
#pragma unroll
      for (int j = 0; j < 4; ++j) {
        union { bf16x8 v; unsigned short u[8]; } hu;
        hu.v = hv[j];
#pragma unroll
        for (int k = 0; k < 8; ++k)
          acc[k] = fmaf(we[j], b2f(hu.u[k]), acc[k]);
      }
    }
  }
  // reduce partial edge-sums across quads (edges distributed mod 4)
#pragma unroll
  for (int k = 0; k < 8; ++k) {
    acc[k] += __shfl_xor(acc[k], 16, 64);
    acc[k] += __shfl_xor(acc[k], 32, 64);
  }
#pragma unroll
  for (int off = 32; off >= 1; off >>= 1) rs += __shfl_xor(rs, off, 64);

  if (lane < 16) {
    float inv = 1.f / rs;
    float o[8];
#pragma unroll
    for (int k = 0; k < 8; ++k) {
      float v = acc[k] * inv;
      o[k] = v > 0.f ? v : expm1f(v);   // elu (alpha=1)
    }
    float4* op = (float4*)(out + ((size_t)b * NN + i) * 128 + lane * 8);
    op[0] = make_float4(o[0], o[1], o[2], o[3]);
    op[1] = make_float4(o[4], o[5], o[6], o[7]);
  }
}

extern "C" void kernel_launch(void* const* d_in, const int* in_sizes, int n_in,
                              void* d_out, int out_size, void* d_ws, size_t ws_size,
                              hipStream_t stream) {
  const float* x = (const float*)d_in[0];
  const float* W = (const float*)d_in[1];
  const float* a = (const float*)d_in[2];
  const int* edge = (const int*)d_in[3];
  const int* src = edge;
  const int* dst = edge + NE;
  float* out = (float*)d_out;

  // workspace layout (~43.7 MB)
  char* p = (char*)d_ws;
  unsigned short* hb = (unsigned short*)p;  p += (size_t)ROWS * 128 * 2;  // 40.96 MB
  float* g1 = (float*)p;                    p += (size_t)ROWS * 4;
  float* g2 = (float*)p;                    p += (size_t)ROWS * 4;
  int* counts = (int*)p;                    p += (size_t)NN * 4;
  int* offsets = (int*)p;                   p += (size_t)(NN + 1) * 4;
  int* cursor = (int*)p;                    p += (size_t)NN * 4;
  int* csr_dst = (int*)p;                   p += (size_t)NE * 4;
  unsigned short* Wb = (unsigned short*)p;  p += (size_t)FI * FO * 2;

  wt_kernel<<<80, 256, 0, stream>>>(W, Wb, counts);  // also zeroes counts
  gemm_kernel<<<ROWS / 64, 256, 0, stream>>>(x, Wb, a, hb, g1, g2);
  hist_kernel<<<(NE + 255) / 256, 256, 0, stream>>>(src, counts);
  scan_kernel<<<1, 1024, 0, stream>>>(counts, offsets, cursor);
  scatter_kernel<<<(NE + 255) / 256, 256, 0, stream>>>(src, dst, cursor, csr_dst);
  gather_kernel<<<(NN / 4) * NB, 256, 0, stream>>>(hb, g1, g2, offsets, csr_dst, out);
}

// Round 2
// 323.189 us; speedup vs baseline: 1.0298x; 1.0298x over previous
//
#include <hip/hip_runtime.h>

#define NB 8
#define NN 20000
#define FI 128
#define FO 128
#define NE 320000
#define ROWS (NB * NN)        // 160000 flattened (b,n) rows
#define LRALPHA 0.2f

typedef short bf16x8 __attribute__((ext_vector_type(8)));
typedef float f32x4 __attribute__((ext_vector_type(4)));

static __device__ __forceinline__ float b2f(unsigned short u) {
  return __uint_as_float(((unsigned int)u) << 16);
}
static __device__ __forceinline__ unsigned short f2b(float f) {
  unsigned int u = __float_as_uint(f);
  return (unsigned short)((u + 0x7FFFu + ((u >> 16) & 1u)) >> 16);  // RNE
}

// ---- W transpose: W[k][o] fp32 -> Wb[o][k] bf16; also zero counts ---------
__global__ __launch_bounds__(256) void wt_kernel(const float* __restrict__ W,
                                                 unsigned short* __restrict__ Wb,
                                                 int* __restrict__ counts) {
  int idx = blockIdx.x * 256 + threadIdx.x;  // 80 blocks -> 20480 threads
  if (idx < FI * FO) {
    int k = idx >> 7, o = idx & 127;
    Wb[o * 128 + k] = f2b(W[idx]);
  }
  if (idx < NN) counts[idx] = 0;
}

// ---- GEMM: W in padded LDS (verified round-0 version); fused g1/g2 --------
#define LDW 136  // padded LDS stride: m-stride 272B -> 2-way bank alias (free)

__global__ __launch_bounds__(256) void gemm_kernel(
    const float* __restrict__ x, const unsigned short* __restrict__ Wb,
    const float* __restrict__ a,
    unsigned short* __restrict__ hb,
    float* __restrict__ g1, float* __restrict__ g2) {
  __shared__ __align__(16) unsigned short Ws[128 * LDW];  // 34.8 KB
  const int tid = threadIdx.x;

  // stage Wb (already bf16, [o][k]) into padded LDS: coalesced 16B chunks
  {
    const bf16x8* wsrc = (const bf16x8*)Wb;
#pragma unroll
    for (int it = 0; it < 8; ++it) {
      int c = tid + it * 256;          // 16B chunk id, 0..2047
      int o = c >> 4, seg = c & 15;
      *(bf16x8*)&Ws[o * LDW + seg * 8] = wsrc[c];
    }
  }

  const int wv = tid >> 6;
  const int lane = tid & 63;
  const int m = lane & 15;
  const int quad = lane >> 4;
  const size_t row0 = (size_t)blockIdx.x * 64 + wv * 16;  // wave's first row

  // A-fragments: x[row0+m][k0*32 + quad*8 .. +8] fp32 -> bf16 in-reg
  const float* xr = x + (row0 + m) * 128;
  bf16x8 afr[4];
#pragma unroll
  for (int k0 = 0; k0 < 4; ++k0) {
    const float4* xp = (const float4*)(xr + k0 * 32 + quad * 8);
    float4 v0 = xp[0];
    float4 v1 = xp[1];
    union { bf16x8 v; unsigned short u[8]; } af;
    af.u[0] = f2b(v0.x); af.u[1] = f2b(v0.y);
    af.u[2] = f2b(v0.z); af.u[3] = f2b(v0.w);
    af.u[4] = f2b(v1.x); af.u[5] = f2b(v1.y);
    af.u[6] = f2b(v1.z); af.u[7] = f2b(v1.w);
    afr[k0] = af.v;
  }
  __syncthreads();

  f32x4 acc[8] = {};
#pragma unroll
  for (int k0 = 0; k0 < 4; ++k0) {
#pragma unroll
    for (int c = 0; c < 8; ++c) {
      bf16x8 bf = *(const bf16x8*)&Ws[(c * 16 + m) * LDW + k0 * 32 + quad * 8];
      acc[c] = __builtin_amdgcn_mfma_f32_16x16x32_bf16(afr[k0], bf, acc[c], 0, 0, 0);
    }
  }

  // C/D layout: col = lane&15 (within c-tile), row = quad*4 + r
  unsigned short* hp = hb + row0 * 128;
#pragma unroll
  for (int c = 0; c < 8; ++c)
#pragma unroll
    for (int r = 0; r < 4; ++r)
      hp[(quad * 4 + r) * 128 + c * 16 + m] = f2b(acc[c][r]);

  // fused g1/g2: per-row dot with a1/a2 from fp32 accumulators
  float a1v[8], a2v[8];
#pragma unroll
  for (int c = 0; c < 8; ++c) {
    a1v[c] = a[c * 16 + m];
    a2v[c] = a[128 + c * 16 + m];
  }
  float p1[4] = {}, p2[4] = {};
#pragma unroll
  for (int c = 0; c < 8; ++c)
#pragma unroll
    for (int r = 0; r < 4; ++r) {
      p1[r] = fmaf(acc[c][r], a1v[c], p1[r]);
      p2[r] = fmaf(acc[c][r], a2v[c], p2[r]);
    }
#pragma unroll
  for (int off = 1; off < 16; off <<= 1)
#pragma unroll
    for (int r = 0; r < 4; ++r) {
      p1[r] += __shfl_xor(p1[r], off, 64);
      p2[r] += __shfl_xor(p2[r], off, 64);
    }
  if (m == 0) {
    size_t rbase = row0 + quad * 4;
#pragma unroll
    for (int r = 0; r < 4; ++r) {
      g1[rbase + r] = p1[r];
      g2[rbase + r] = p2[r];
    }
  }
}

// ---------------- CSR build: histogram -> scan -> scatter -------------------
__global__ __launch_bounds__(256) void hist_kernel(const int* __restrict__ src,
                                                   int* __restrict__ counts) {
  int e = blockIdx.x * 256 + threadIdx.x;
  if (e < NE) atomicAdd(&counts[src[e]], 1);
}

__global__ __launch_bounds__(1024) void scan_kernel(
    const int* __restrict__ counts, int* __restrict__ offsets,
    int* __restrict__ cursor) {
  __shared__ int sc[NN];      // 80 KB
  __shared__ int sums[1024];
  const int t = threadIdx.x;
  for (int idx = t; idx < NN; idx += 1024) sc[idx] = counts[idx];  // coalesced
  __syncthreads();
  int local[20];
  int base = t * 20;
  int s = 0;
#pragma unroll
  for (int c = 0; c < 20; ++c) {
    int idx = base + c;
    int v = (idx < NN) ? sc[idx] : 0;
    local[c] = s;
    s += v;
  }
  sums[t] = s;
  __syncthreads();
  for (int off = 1; off < 1024; off <<= 1) {
    int u = 0;
    if (t >= off) u = sums[t - off];
    __syncthreads();
    sums[t] += u;
    __syncthreads();
  }
  int prefix = sums[t] - s;  // exclusive over threads
#pragma unroll
  for (int c = 0; c < 20; ++c) {
    int idx = base + c;
    if (idx < NN) {
      int o = prefix + local[c];
      offsets[idx] = o;
      cursor[idx] = o;
    }
  }
  if (t == 0) offsets[NN] = NE;
}

// scatter: store dst (and src) at CSR position
__global__ __launch_bounds__(256) void scatter_kernel(
    const int* __restrict__ src, const int* __restrict__ dst,
    int* __restrict__ cursor, int* __restrict__ csr_dst,
    int* __restrict__ csr_src) {
  int e = blockIdx.x * 256 + threadIdx.x;
  if (e < NE) {
    int s = src[e];
    int d = dst[e];
    int pos = atomicAdd(&cursor[s], 1);
    csr_dst[pos] = d;
    csr_src[pos] = s;
  }
}

// ---- edge weights, fully coalesced: w[b][pos] = exp(-lrelu(g1[s]+g2[d])) --
__global__ __launch_bounds__(256) void weight_kernel(
    const int* __restrict__ csr_src, const int* __restrict__ csr_dst,
    const float* __restrict__ g1, const float* __restrict__ g2,
    float* __restrict__ wcsr) {
  int pos = blockIdx.x * 256 + threadIdx.x;
  int b = blockIdx.y;
  if (pos < NE) {
    int s = csr_src[pos];
    int d = csr_dst[pos];
    float sv = g1[(size_t)b * NN + s] + g2[(size_t)b * NN + d];
    float sc = fmaxf(sv, LRALPHA * sv);
    wcsr[(size_t)b * NE + pos] = __expf(-sc);
  }
}

// ---------------- gather: per (node i, batch b) segment reduce --------------
// Latency-optimized: weights precomputed; inner loop is only
//   csr_dst[p] (quad-uniform broadcast) -> h-row 16B load -> fma
// with the weight load in parallel. No shfl/exp/g2-gather on the chain.
// XCD-affine batch (bid&7); 4 nodes per 256-thread block (independent waves).
__global__ __launch_bounds__(256) void gather_kernel(
    const unsigned short* __restrict__ hb, const float* __restrict__ wcsr,
    const int* __restrict__ offsets, const int* __restrict__ csr_dst,
    float* __restrict__ out) {
  const int bid = blockIdx.x;
  const int b = bid & 7;            // XCD-affine batch
  const int chunk = bid >> 3;
  const int wv = threadIdx.x >> 6;
  const int i = chunk * 4 + wv;     // node handled by this wave
  const int lane = threadIdx.x & 63;
  const int quad = lane >> 4;
  const int beg = offsets[i];
  const int deg = offsets[i + 1] - beg;
  const float* wb_ = wcsr + (size_t)b * NE;
  // lane's 16B slice within any h-row of batch b
  const char* hbase = (const char*)(hb + (size_t)b * NN * 128) + (lane & 15) * 16;

  float acc[8] = {};
  float rs = 0.f;
  for (int c0 = 0; c0 < deg; c0 += 16) {
    bf16x8 hv[4];
    float we[4];
#pragma unroll
    for (int j = 0; j < 4; ++j) {
      int idx = c0 + j * 4 + quad;
      bool v = idx < deg;
      int p = beg + (v ? idx : 0);
      int d = csr_dst[p];                 // 16 lanes same addr: broadcast
      we[j] = v ? wb_[p] : 0.f;           // parallel, not on h-chain
      hv[j] = *(const bf16x8*)(hbase + ((size_t)d << 8));
    }
#pragma unroll
    for (int j = 0; j < 4; ++j) {
      rs += we[j];                        // quad-lanes hold identical partials
      union { bf16x8 v; unsigned short u[8]; } hu;
      hu.v = hv[j];
#pragma unroll
      for (int k = 0; k < 8; ++k)
        acc[k] = fmaf(we[j], b2f(hu.u[k]), acc[k]);
    }
  }
  // cross-quad reduce: lanes within a quad are identical for rs, partial for acc
#pragma unroll
  for (int k = 0; k < 8; ++k) {
    acc[k] += __shfl_xor(acc[k], 16, 64);
    acc[k] += __shfl_xor(acc[k], 32, 64);
  }
  rs += __shfl_xor(rs, 16, 64);
  rs += __shfl_xor(rs, 32, 64);           // exact rowsum (quad copies identical)

  if (lane < 16) {
    float inv = 1.f / rs;
    float o[8];
#pragma unroll
    for (int k = 0; k < 8; ++k) {
      float v = acc[k] * inv;
      o[k] = v > 0.f ? v : expm1f(v);   // elu (alpha=1)
    }
    float4* op = (float4*)(out + ((size_t)b * NN + i) * 128 + lane * 8);
    op[0] = make_float4(o[0], o[1], o[2], o[3]);
    op[1] = make_float4(o[4], o[5], o[6], o[7]);
  }
}

extern "C" void kernel_launch(void* const* d_in, const int* in_sizes, int n_in,
                              void* d_out, int out_size, void* d_ws, size_t ws_size,
                              hipStream_t stream) {
  const float* x = (const float*)d_in[0];
  const float* W = (const float*)d_in[1];
  const float* a = (const float*)d_in[2];
  const int* edge = (const int*)d_in[3];
  const int* src = edge;
  const int* dst = edge + NE;
  float* out = (float*)d_out;

  // workspace layout (~55.2 MB)
  char* p = (char*)d_ws;
  unsigned short* hb = (unsigned short*)p;  p += (size_t)ROWS * 128 * 2;  // 40.96 MB
  float* g1 = (float*)p;                    p += (size_t)ROWS * 4;
  float* g2 = (float*)p;                    p += (size_t)ROWS * 4;
  int* counts = (int*)p;                    p += (size_t)NN * 4;
  int* offsets = (int*)p;                   p += (size_t)(NN + 1) * 4;
  int* cursor = (int*)p;                    p += (size_t)NN * 4;
  int* csr_dst = (int*)p;                   p += (size_t)NE * 4;
  int* csr_src = (int*)p;                   p += (size_t)NE * 4;
  float* wcsr = (float*)p;                  p += (size_t)NB * NE * 4;    // 10.24 MB
  unsigned short* Wb = (unsigned short*)p;  p += (size_t)FI * FO * 2;

  wt_kernel<<<80, 256, 0, stream>>>(W, Wb, counts);  // also zeroes counts
  gemm_kernel<<<ROWS / 64, 256, 0, stream>>>(x, Wb, a, hb, g1, g2);
  hist_kernel<<<(NE + 255) / 256, 256, 0, stream>>>(src, counts);
  scan_kernel<<<1, 1024, 0, stream>>>(counts, offsets, cursor);
  scatter_kernel<<<(NE + 255) / 256, 256, 0, stream>>>(src, dst, cursor, csr_dst, csr_src);
  dim3 wgrid((NE + 255) / 256, NB);
  weight_kernel<<<wgrid, 256, 0, stream>>>(csr_src, csr_dst, g1, g2, wcsr);
  gather_kernel<<<(NN / 4) * NB, 256, 0, stream>>>(hb, wcsr, offsets, csr_dst, out);
}

// Round 3
// 310.694 us; speedup vs baseline: 1.0712x; 1.0402x over previous
//
#include <hip/hip_runtime.h>

#define NB 8
#define NN 20000
#define FI 128
#define FO 128
#define NE 320000
#define ROWS (NB * NN)        // 160000 flattened (b,n) rows
#define LRALPHA 0.2f

typedef short bf16x8 __attribute__((ext_vector_type(8)));
typedef float f32x4 __attribute__((ext_vector_type(4)));

static __device__ __forceinline__ float b2f(unsigned short u) {
  return __uint_as_float(((unsigned int)u) << 16);
}
static __device__ __forceinline__ unsigned short f2b(float f) {
  unsigned int u = __float_as_uint(f);
  return (unsigned short)((u + 0x7FFFu + ((u >> 16) & 1u)) >> 16);  // RNE
}

// ---- W transpose: W[k][o] fp32 -> Wb[o][k] bf16; also zero counts ---------
__global__ __launch_bounds__(256) void wt_kernel(const float* __restrict__ W,
                                                 unsigned short* __restrict__ Wb,
                                                 int* __restrict__ counts) {
  int idx = blockIdx.x * 256 + threadIdx.x;  // 80 blocks -> 20480 threads
  if (idx < FI * FO) {
    int k = idx >> 7, o = idx & 127;
    Wb[o * 128 + k] = f2b(W[idx]);
  }
  if (idx < NN) counts[idx] = 0;
}

// ---- GEMM: W in padded LDS; outputs to TRANSPOSED layouts -----------------
// hbT[n][b][128] bf16, g1T/g2T[n][b] f32.
#define LDW 136  // padded LDS stride: m-stride 272B -> 2-way bank alias (free)

__global__ __launch_bounds__(256) void gemm_kernel(
    const float* __restrict__ x, const unsigned short* __restrict__ Wb,
    const float* __restrict__ a,
    unsigned short* __restrict__ hbT,
    float* __restrict__ g1T, float* __restrict__ g2T) {
  __shared__ __align__(16) unsigned short Ws[128 * LDW];  // 34.8 KB
  const int tid = threadIdx.x;

  // stage Wb (already bf16, [o][k]) into padded LDS: coalesced 16B chunks
  {
    const bf16x8* wsrc = (const bf16x8*)Wb;
#pragma unroll
    for (int it = 0; it < 8; ++it) {
      int c = tid + it * 256;          // 16B chunk id, 0..2047
      int o = c >> 4, seg = c & 15;
      *(bf16x8*)&Ws[o * LDW + seg * 8] = wsrc[c];
    }
  }

  const int wv = tid >> 6;
  const int lane = tid & 63;
  const int m = lane & 15;
  const int quad = lane >> 4;
  const size_t row0 = (size_t)blockIdx.x * 64 + wv * 16;  // wave's first row
  // wave tiles (16 rows) never cross a batch boundary (20000 % 16 == 0)
  const int b = (int)(row0 / NN);
  const int n0 = (int)(row0 - (size_t)b * NN);

  // A-fragments: x[row0+m][k0*32 + quad*8 .. +8] fp32 -> bf16 in-reg
  const float* xr = x + (row0 + m) * 128;
  bf16x8 afr[4];
#pragma unroll
  for (int k0 = 0; k0 < 4; ++k0) {
    const float4* xp = (const float4*)(xr + k0 * 32 + quad * 8);
    float4 v0 = xp[0];
    float4 v1 = xp[1];
    union { bf16x8 v; unsigned short u[8]; } af;
    af.u[0] = f2b(v0.x); af.u[1] = f2b(v0.y);
    af.u[2] = f2b(v0.z); af.u[3] = f2b(v0.w);
    af.u[4] = f2b(v1.x); af.u[5] = f2b(v1.y);
    af.u[6] = f2b(v1.z); af.u[7] = f2b(v1.w);
    afr[k0] = af.v;
  }
  __syncthreads();

  f32x4 acc[8] = {};
#pragma unroll
  for (int k0 = 0; k0 < 4; ++k0) {
#pragma unroll
    for (int c = 0; c < 8; ++c) {
      bf16x8 bf = *(const bf16x8*)&Ws[(c * 16 + m) * LDW + k0 * 32 + quad * 8];
      acc[c] = __builtin_amdgcn_mfma_f32_16x16x32_bf16(afr[k0], bf, acc[c], 0, 0, 0);
    }
  }

  // C/D layout: col = lane&15 (within c-tile), row = quad*4 + r
  // store to hbT[n][b][128]: n-stride = 8*128 shorts
  unsigned short* hp = hbT + ((size_t)n0 * 8 + b) * 128;
#pragma unroll
  for (int c = 0; c < 8; ++c)
#pragma unroll
    for (int r = 0; r < 4; ++r)
      hp[(size_t)(quad * 4 + r) * 1024 + c * 16 + m] = f2b(acc[c][r]);

  // fused g1/g2: per-row dot with a1/a2 from fp32 accumulators
  float a1v[8], a2v[8];
#pragma unroll
  for (int c = 0; c < 8; ++c) {
    a1v[c] = a[c * 16 + m];
    a2v[c] = a[128 + c * 16 + m];
  }
  float p1[4] = {}, p2[4] = {};
#pragma unroll
  for (int c = 0; c < 8; ++c)
#pragma unroll
    for (int r = 0; r < 4; ++r) {
      p1[r] = fmaf(acc[c][r], a1v[c], p1[r]);
      p2[r] = fmaf(acc[c][r], a2v[c], p2[r]);
    }
#pragma unroll
  for (int off = 1; off < 16; off <<= 1)
#pragma unroll
    for (int r = 0; r < 4; ++r) {
      p1[r] += __shfl_xor(p1[r], off, 64);
      p2[r] += __shfl_xor(p2[r], off, 64);
    }
  if (m == 0) {
    int nb = n0 + quad * 4;
#pragma unroll
    for (int r = 0; r < 4; ++r) {
      g1T[(size_t)(nb + r) * 8 + b] = p1[r];
      g2T[(size_t)(nb + r) * 8 + b] = p2[r];
    }
  }
}

// ---------------- CSR build: histogram -> scan -> scatter+weights ----------
__global__ __launch_bounds__(256) void hist_kernel(const int* __restrict__ src,
                                                   int* __restrict__ counts) {
  int e = blockIdx.x * 256 + threadIdx.x;
  if (e < NE) atomicAdd(&counts[src[e]], 1);
}

__global__ __launch_bounds__(1024) void scan_kernel(
    const int* __restrict__ counts, int* __restrict__ offsets,
    int* __restrict__ cursor) {
  __shared__ int sc[NN];      // 80 KB
  __shared__ int sums[1024];
  const int t = threadIdx.x;
  for (int idx = t; idx < NN; idx += 1024) sc[idx] = counts[idx];  // coalesced
  __syncthreads();
  int local[20];
  int base = t * 20;
  int s = 0;
#pragma unroll
  for (int c = 0; c < 20; ++c) {
    int idx = base + c;
    int v = (idx < NN) ? sc[idx] : 0;
    local[c] = s;
    s += v;
  }
  sums[t] = s;
  __syncthreads();
  for (int off = 1; off < 1024; off <<= 1) {
    int u = 0;
    if (t >= off) u = sums[t - off];
    __syncthreads();
    sums[t] += u;
    __syncthreads();
  }
  int prefix = sums[t] - s;  // exclusive over threads
#pragma unroll
  for (int c = 0; c < 20; ++c) {
    int idx = base + c;
    if (idx < NN) {
      int o = prefix + local[c];
      offsets[idx] = o;
      cursor[idx] = o;
    }
  }
  if (t == 0) offsets[NN] = NE;
}

// scatter + fused edge weights: csr_dst[pos]=d and wT[pos][b]=exp(-lrelu(.))
__global__ __launch_bounds__(256) void scatter_kernel(
    const int* __restrict__ src, const int* __restrict__ dst,
    int* __restrict__ cursor, int* __restrict__ csr_dst,
    const float* __restrict__ g1T, const float* __restrict__ g2T,
    float* __restrict__ wT) {
  int e = blockIdx.x * 256 + threadIdx.x;
  if (e < NE) {
    int s = src[e];
    int d = dst[e];
    int pos = atomicAdd(&cursor[s], 1);
    csr_dst[pos] = d;
    const float4* g1p = (const float4*)(g1T + (size_t)s * 8);
    const float4* g2p = (const float4*)(g2T + (size_t)d * 8);
    float4 sa = g1p[0], sb = g1p[1];
    float4 da = g2p[0], db = g2p[1];
    float sv[8] = {sa.x + da.x, sa.y + da.y, sa.z + da.z, sa.w + da.w,
                   sb.x + db.x, sb.y + db.y, sb.z + db.z, sb.w + db.w};
    float w[8];
#pragma unroll
    for (int bi = 0; bi < 8; ++bi) {
      float sc = fmaxf(sv[bi], LRALPHA * sv[bi]);
      w[bi] = __expf(-sc);
    }
    float4* wp = (float4*)(wT + (size_t)pos * 8);
    wp[0] = make_float4(w[0], w[1], w[2], w[3]);
    wp[1] = make_float4(w[4], w[5], w[6], w[7]);
  }
}

// ---------------- gather: one node x ALL 8 batches per wave -----------------
// hbT[n][b][128]: one edge's 8 batch-rows = 2KB contiguous = 64 lanes x 32B.
// Lane owns (batch=lane>>3, col-slice=lane&7): 16 f32 acc, zero cross-lane
// reduces (rowsum replicated within 8-lane groups via broadcast loads).
__global__ __launch_bounds__(256) void gather_kernel(
    const unsigned short* __restrict__ hbT, const float* __restrict__ wT,
    const int* __restrict__ offsets, const int* __restrict__ csr_dst,
    float* __restrict__ out) {
  const int i = blockIdx.x * 4 + (threadIdx.x >> 6);  // node for this wave
  const int lane = threadIdx.x & 63;
  const int bq = lane >> 3;          // batch
  const int sl = lane & 7;           // 16-col slice
  const int beg = offsets[i];
  const int deg = offsets[i + 1] - beg;   // >= 1 (src contains arange(N))
  const char* hl = (const char*)hbT + (size_t)lane * 32;
  const float* wl = wT + bq;

  float acc[16] = {};
  float rs = 0.f;
  int c0 = 0;
  int dvec = csr_dst[beg + min(lane & 15, deg - 1)];  // chunk [0,16) clamped

  // full 16-edge chunks: compile-time unrolled for ILP
  for (; c0 + 16 <= deg; c0 += 16) {
    int dnext = csr_dst[beg + min(c0 + 16 + (lane & 15), deg - 1)];
#pragma unroll
    for (int j = 0; j < 16; ++j) {
      int d = __shfl(dvec, j, 16);                  // broadcast edge j
      float w = wl[(size_t)(beg + c0 + j) * 8];     // 8-lane broadcast
      const char* hp = hl + ((size_t)d << 11);
      bf16x8 h0 = *(const bf16x8*)hp;
      bf16x8 h1 = *(const bf16x8*)(hp + 16);
      rs += w;
      union { bf16x8 v; unsigned short u[8]; } a0, a1;
      a0.v = h0; a1.v = h1;
#pragma unroll
      for (int k = 0; k < 8; ++k) {
        acc[k]     = fmaf(w, b2f(a0.u[k]), acc[k]);
        acc[8 + k] = fmaf(w, b2f(a1.u[k]), acc[8 + k]);
      }
    }
    dvec = dnext;
  }
  // masked tail, unroll-4 (dvec holds chunk [c0, c0+16) clamped)
  {
    const int lim = deg - c0;  // 0..15
    for (int t = 0; t < lim; t += 4) {
#pragma unroll
      for (int j = 0; j < 4; ++j) {
        int u = t + j;
        bool v = u < lim;
        int d = __shfl(dvec, v ? u : (lim - 1), 16);
        float w = v ? wl[(size_t)(beg + c0 + u) * 8] : 0.f;
        const char* hp = hl + ((size_t)d << 11);
        bf16x8 h0 = *(const bf16x8*)hp;
        bf16x8 h1 = *(const bf16x8*)(hp + 16);
        rs += w;
        union { bf16x8 v; unsigned short u8[8]; } a0, a1;
        a0.v = h0; a1.v = h1;
#pragma unroll
        for (int k = 0; k < 8; ++k) {
          acc[k]     = fmaf(w, b2f(a0.u8[k]), acc[k]);
          acc[8 + k] = fmaf(w, b2f(a1.u8[k]), acc[8 + k]);
        }
      }
    }
  }

  float inv = 1.f / rs;
  float o[16];
#pragma unroll
  for (int k = 0; k < 16; ++k) {
    float v = acc[k] * inv;
    o[k] = v > 0.f ? v : expm1f(v);   // elu (alpha=1)
  }
  float* op = out + ((size_t)bq * NN + i) * 128 + sl * 16;
  float4* op4 = (float4*)op;
  op4[0] = make_float4(o[0], o[1], o[2], o[3]);
  op4[1] = make_float4(o[4], o[5], o[6], o[7]);
  op4[2] = make_float4(o[8], o[9], o[10], o[11]);
  op4[3] = make_float4(o[12], o[13], o[14], o[15]);
}

extern "C" void kernel_launch(void* const* d_in, const int* in_sizes, int n_in,
                              void* d_out, int out_size, void* d_ws, size_t ws_size,
                              hipStream_t stream) {
  const float* x = (const float*)d_in[0];
  const float* W = (const float*)d_in[1];
  const float* a = (const float*)d_in[2];
  const int* edge = (const int*)d_in[3];
  const int* src = edge;
  const int* dst = edge + NE;
  float* out = (float*)d_out;

  // workspace layout (~54 MB)
  char* p = (char*)d_ws;
  unsigned short* hbT = (unsigned short*)p; p += (size_t)ROWS * 128 * 2;  // 40.96 MB
  float* g1T = (float*)p;                   p += (size_t)ROWS * 4;
  float* g2T = (float*)p;                   p += (size_t)ROWS * 4;
  int* counts = (int*)p;                    p += (size_t)NN * 4;
  int* offsets = (int*)p;                   p += (size_t)(NN + 1) * 4;
  int* cursor = (int*)p;                    p += (size_t)NN * 4;
  int* csr_dst = (int*)p;                   p += (size_t)NE * 4;
  float* wT = (float*)p;                    p += (size_t)NE * 8 * 4;     // 10.24 MB
  unsigned short* Wb = (unsigned short*)p;  p += (size_t)FI * FO * 2;

  wt_kernel<<<80, 256, 0, stream>>>(W, Wb, counts);  // also zeroes counts
  gemm_kernel<<<ROWS / 64, 256, 0, stream>>>(x, Wb, a, hbT, g1T, g2T);
  hist_kernel<<<(NE + 255) / 256, 256, 0, stream>>>(src, counts);
  scan_kernel<<<1, 1024, 0, stream>>>(counts, offsets, cursor);
  scatter_kernel<<<(NE + 255) / 256, 256, 0, stream>>>(src, dst, cursor, csr_dst,
                                                       g1T, g2T, wT);
  gather_kernel<<<NN / 4, 256, 0, stream>>>(hbT, wT, offsets, csr_dst, out);
}

// Round 6
// 289.848 us; speedup vs baseline: 1.1482x; 1.0719x over previous
//
#include <hip/hip_runtime.h>

#define NB 8
#define NN 20000
#define FI 128
#define FO 128
#define NE 320000
#define ROWS (NB * NN)        // 160000 flattened (b,n) rows
#define LRALPHA 0.2f
#define ELLW 96               // max degree slot; Poisson(16) tail ~1e-43

typedef short bf16x8 __attribute__((ext_vector_type(8)));
typedef float f32x4 __attribute__((ext_vector_type(4)));

static __device__ __forceinline__ float b2f(unsigned short u) {
  return __uint_as_float(((unsigned int)u) << 16);
}
static __device__ __forceinline__ unsigned short f2b(float f) {
  unsigned int u = __float_as_uint(f);
  return (unsigned short)((u + 0x7FFFu + ((u >> 16) & 1u)) >> 16);  // RNE
}

// ---- W transpose: W[k][o] fp32 -> Wb[o][k] bf16; also zero ELL cursor -----
__global__ __launch_bounds__(256) void wt_kernel(const float* __restrict__ W,
                                                 unsigned short* __restrict__ Wb,
                                                 int* __restrict__ cursor) {
  int idx = blockIdx.x * 256 + threadIdx.x;  // 80 blocks -> 20480 threads
  if (idx < FI * FO) {
    int k = idx >> 7, o = idx & 127;
    Wb[o * 128 + k] = f2b(W[idx]);
  }
  if (idx < NN) cursor[idx] = 0;
}

// ---- GEMM: W in padded LDS (round-0 verified); hb[b][n][128] bf16 ---------
#define LDW 136  // padded LDS stride: m-stride 272B -> 2-way bank alias (free)

__global__ __launch_bounds__(256) void gemm_kernel(
    const float* __restrict__ x, const unsigned short* __restrict__ Wb,
    const float* __restrict__ a,
    unsigned short* __restrict__ hb,
    float* __restrict__ g1, float* __restrict__ g2) {
  __shared__ __align__(16) unsigned short Ws[128 * LDW];  // 34.8 KB
  const int tid = threadIdx.x;

  // stage Wb (already bf16, [o][k]) into padded LDS: coalesced 16B chunks
  {
    const bf16x8* wsrc = (const bf16x8*)Wb;
#pragma unroll
    for (int it = 0; it < 8; ++it) {
      int c = tid + it * 256;          // 16B chunk id, 0..2047
      int o = c >> 4, seg = c & 15;
      *(bf16x8*)&Ws[o * LDW + seg * 8] = wsrc[c];
    }
  }

  const int wv = tid >> 6;
  const int lane = tid & 63;
  const int m = lane & 15;
  const int quad = lane >> 4;
  const size_t row0 = (size_t)blockIdx.x * 64 + wv * 16;  // wave's first row

  // A-fragments: x[row0+m][k0*32 + quad*8 .. +8] fp32 -> bf16 in-reg
  const float* xr = x + (row0 + m) * 128;
  bf16x8 afr[4];
#pragma unroll
  for (int k0 = 0; k0 < 4; ++k0) {
    const float4* xp = (const float4*)(xr + k0 * 32 + quad * 8);
    float4 v0 = xp[0];
    float4 v1 = xp[1];
    union { bf16x8 v; unsigned short u[8]; } af;
    af.u[0] = f2b(v0.x); af.u[1] = f2b(v0.y);
    af.u[2] = f2b(v0.z); af.u[3] = f2b(v0.w);
    af.u[4] = f2b(v1.x); af.u[5] = f2b(v1.y);
    af.u[6] = f2b(v1.z); af.u[7] = f2b(v1.w);
    afr[k0] = af.v;
  }
  __syncthreads();

  f32x4 acc[8] = {};
#pragma unroll
  for (int k0 = 0; k0 < 4; ++k0) {
#pragma unroll
    for (int c = 0; c < 8; ++c) {
      bf16x8 bf = *(const bf16x8*)&Ws[(c * 16 + m) * LDW + k0 * 32 + quad * 8];
      acc[c] = __builtin_amdgcn_mfma_f32_16x16x32_bf16(afr[k0], bf, acc[c], 0, 0, 0);
    }
  }

  // C/D layout: col = lane&15 (within c-tile), row = quad*4 + r
  unsigned short* hp = hb + row0 * 128;
#pragma unroll
  for (int c = 0; c < 8; ++c)
#pragma unroll
    for (int r = 0; r < 4; ++r)
      hp[(quad * 4 + r) * 128 + c * 16 + m] = f2b(acc[c][r]);

  // fused g1/g2: per-row dot with a1/a2 from fp32 accumulators
  float a1v[8], a2v[8];
#pragma unroll
  for (int c = 0; c < 8; ++c) {
    a1v[c] = a[c * 16 + m];
    a2v[c] = a[128 + c * 16 + m];
  }
  float p1[4] = {}, p2[4] = {};
#pragma unroll
  for (int c = 0; c < 8; ++c)
#pragma unroll
    for (int r = 0; r < 4; ++r) {
      p1[r] = fmaf(acc[c][r], a1v[c], p1[r]);
      p2[r] = fmaf(acc[c][r], a2v[c], p2[r]);
    }
#pragma unroll
  for (int off = 1; off < 16; off <<= 1)
#pragma unroll
    for (int r = 0; r < 4; ++r) {
      p1[r] += __shfl_xor(p1[r], off, 64);
      p2[r] += __shfl_xor(p2[r], off, 64);
    }
  if (m == 0) {
    size_t rbase = row0 + quad * 4;
#pragma unroll
    for (int r = 0; r < 4; ++r) {
      g1[rbase + r] = p1[r];
      g2[rbase + r] = p2[r];
    }
  }
}

// ---- ELL scatter: one pass, replaces hist+scan+scatter --------------------
__global__ __launch_bounds__(256) void ell_scatter_kernel(
    const int* __restrict__ src, const int* __restrict__ dst,
    int* __restrict__ cursor, int* __restrict__ ell) {
  int e = blockIdx.x * 256 + threadIdx.x;
  if (e < NE) {
    int s = src[e];
    int d = dst[e];
    int slot = atomicAdd(&cursor[s], 1);
    if (slot < ELLW) ell[s * ELLW + slot] = d;   // overflow impossible; clamp for safety
  }
}

// ---------------- gather: fat waves + batch-XCD affinity --------------------
// hb[b][n][128] bf16 batch-major: each XCD (batch = bid&7, round-robin
// dispatch) touches only its 5.12 MB batch slice -> L2-resident h reuse.
// Wave handles (node i, batch b); 8 lane-groups process 8 edges in parallel,
// each group's 8 lanes cover the 128-col row (16 cols = 32B per lane).
__global__ __launch_bounds__(256) void gather_kernel(
    const unsigned short* __restrict__ hb, const float* __restrict__ g1,
    const float* __restrict__ g2, const int* __restrict__ degs,
    const int* __restrict__ ell, float* __restrict__ out) {
  const int bid = blockIdx.x;
  const int b = bid & 7;                     // XCD-affine batch
  const int wv = threadIdx.x >> 6;
  const int i = (bid >> 3) * 4 + wv;         // node for this wave
  const int lane = threadIdx.x & 63;
  const int group = lane >> 3;               // edge slot within 8-wide batch
  const int sub = lane & 7;                  // 16-col slice within row
  const int deg = min(degs[i], ELLW);        // >= 1 (src contains arange(N))
  const int base = i * ELLW;
  const float g1i = g1[(size_t)b * NN + i];
  const float* g2b = g2 + (size_t)b * NN;
  const unsigned short* hbb = hb + (size_t)b * NN * 128;

  float acc[16] = {};
  float rs = 0.f;
  for (int c0 = 0; c0 < deg; c0 += 64) {
    const int cnt = min(64, deg - c0);
    const int li = lane < cnt ? lane : cnt - 1;
    const int dvec = ell[base + c0 + li];    // coalesced chunk of dst indices
    float w = 0.f;
    if (lane < cnt) {
      float sv = g1i + g2b[dvec];            // L2-resident 4B gather
      float sc = fmaxf(sv, LRALPHA * sv);
      w = __expf(-sc);
    }
    rs += w;
    const int iters = (cnt + 7) >> 3;
    for (int t = 0; t < iters; ++t) {
      const int sel = t * 8 + group;         // this group's edge in the chunk
      float wg = __shfl(w, sel, 64);         // 0 for padded slots
      int dg = __shfl(dvec, sel, 64);        // clamped for padded slots (safe)
      const bf16x8* hp = (const bf16x8*)(hbb + (size_t)dg * 128 + sub * 16);
      union { bf16x8 v; unsigned short u[8]; } h0, h1;
      h0.v = hp[0];
      h1.v = hp[1];
#pragma unroll
      for (int k = 0; k < 8; ++k) {
        acc[k]     = fmaf(wg, b2f(h0.u[k]), acc[k]);
        acc[8 + k] = fmaf(wg, b2f(h1.u[k]), acc[8 + k]);
      }
    }
  }
  // reduce edge-partials across the 8 groups (edges distributed mod 8)
#pragma unroll
  for (int k = 0; k < 16; ++k) {
    acc[k] += __shfl_xor(acc[k], 8, 64);
    acc[k] += __shfl_xor(acc[k], 16, 64);
    acc[k] += __shfl_xor(acc[k], 32, 64);
  }
#pragma unroll
  for (int off = 1; off < 64; off <<= 1) rs += __shfl_xor(rs, off, 64);

  if (lane < 8) {
    float inv = 1.f / rs;
    float o[16];
#pragma unroll
    for (int k = 0; k < 16; ++k) {
      float v = acc[k] * inv;
      o[k] = v > 0.f ? v : expm1f(v);   // elu (alpha=1)
    }
    float4* op = (float4*)(out + ((size_t)b * NN + i) * 128 + sub * 16);
    op[0] = make_float4(o[0], o[1], o[2], o[3]);
    op[1] = make_float4(o[4], o[5], o[6], o[7]);
    op[2] = make_float4(o[8], o[9], o[10], o[11]);
    op[3] = make_float4(o[12], o[13], o[14], o[15]);
  }
}

extern "C" void kernel_launch(void* const* d_in, const int* in_sizes, int n_in,
                              void* d_out, int out_size, void* d_ws, size_t ws_size,
                              hipStream_t stream) {
  const float* x = (const float*)d_in[0];
  const float* W = (const float*)d_in[1];
  const float* a = (const float*)d_in[2];
  const int* edge = (const int*)d_in[3];
  const int* src = edge;
  const int* dst = edge + NE;
  float* out = (float*)d_out;

  // workspace layout (~50 MB)
  char* p = (char*)d_ws;
  unsigned short* hb = (unsigned short*)p;  p += (size_t)ROWS * 128 * 2;   // 40.96 MB
  float* g1 = (float*)p;                    p += (size_t)ROWS * 4;
  float* g2 = (float*)p;                    p += (size_t)ROWS * 4;
  int* cursor = (int*)p;                    p += (size_t)NN * 4;
  int* ell = (int*)p;                       p += (size_t)NN * ELLW * 4;   // 7.68 MB
  unsigned short* Wb = (unsigned short*)p;  p += (size_t)FI * FO * 2;

  wt_kernel<<<80, 256, 0, stream>>>(W, Wb, cursor);  // also zeroes cursor
  gemm_kernel<<<ROWS / 64, 256, 0, stream>>>(x, Wb, a, hb, g1, g2);
  ell_scatter_kernel<<<(NE + 255) / 256, 256, 0, stream>>>(src, dst, cursor, ell);
  gather_kernel<<<(NN / 4) * NB, 256, 0, stream>>>(hb, g1, g2, cursor, ell, out);
}

// Round 7
// 260.126 us; speedup vs baseline: 1.2794x; 1.1143x over previous
//
#include <hip/hip_runtime.h>

#define NB 8
#define NN 20000
#define FI 128
#define FO 128
#define NE 320000
#define ROWS (NB * NN)        // 160000 flattened (b,n) rows
#define LRALPHA 0.2f
#define ELLW 96               // max degree slot; Poisson(16) tail ~1e-43

typedef short bf16x8 __attribute__((ext_vector_type(8)));
typedef float f32x4 __attribute__((ext_vector_type(4)));

static __device__ __forceinline__ float b2f(unsigned short u) {
  return __uint_as_float(((unsigned int)u) << 16);
}
static __device__ __forceinline__ unsigned short f2b(float f) {
  unsigned int u = __float_as_uint(f);
  return (unsigned short)((u + 0x7FFFu + ((u >> 16) & 1u)) >> 16);  // RNE
}

// ---- W transpose: W[k][o] fp32 -> Wb[o][k] bf16; also zero ELL cursor -----
__global__ __launch_bounds__(256) void wt_kernel(const float* __restrict__ W,
                                                 unsigned short* __restrict__ Wb,
                                                 int* __restrict__ cursor) {
  int idx = blockIdx.x * 256 + threadIdx.x;  // 80 blocks -> 20480 threads
  if (idx < FI * FO) {
    int k = idx >> 7, o = idx & 127;
    Wb[o * 128 + k] = f2b(W[idx]);
  }
  if (idx < NN) cursor[idx] = 0;
}

// ---- GEMM: W in padded LDS (round-0 verified); hb[b][n][128] bf16 ---------
#define LDW 136  // padded LDS stride: m-stride 272B -> 2-way bank alias (free)

__global__ __launch_bounds__(256) void gemm_kernel(
    const float* __restrict__ x, const unsigned short* __restrict__ Wb,
    const float* __restrict__ a,
    unsigned short* __restrict__ hb,
    float* __restrict__ g1, float* __restrict__ g2) {
  __shared__ __align__(16) unsigned short Ws[128 * LDW];  // 34.8 KB
  const int tid = threadIdx.x;

  // stage Wb (already bf16, [o][k]) into padded LDS: coalesced 16B chunks
  {
    const bf16x8* wsrc = (const bf16x8*)Wb;
#pragma unroll
    for (int it = 0; it < 8; ++it) {
      int c = tid + it * 256;          // 16B chunk id, 0..2047
      int o = c >> 4, seg = c & 15;
      *(bf16x8*)&Ws[o * LDW + seg * 8] = wsrc[c];
    }
  }

  const int wv = tid >> 6;
  const int lane = tid & 63;
  const int m = lane & 15;
  const int quad = lane >> 4;
  const size_t row0 = (size_t)blockIdx.x * 64 + wv * 16;  // wave's first row

  // A-fragments: x[row0+m][k0*32 + quad*8 .. +8] fp32 -> bf16 in-reg
  const float* xr = x + (row0 + m) * 128;
  bf16x8 afr[4];
#pragma unroll
  for (int k0 = 0; k0 < 4; ++k0) {
    const float4* xp = (const float4*)(xr + k0 * 32 + quad * 8);
    float4 v0 = xp[0];
    float4 v1 = xp[1];
    union { bf16x8 v; unsigned short u[8]; } af;
    af.u[0] = f2b(v0.x); af.u[1] = f2b(v0.y);
    af.u[2] = f2b(v0.z); af.u[3] = f2b(v0.w);
    af.u[4] = f2b(v1.x); af.u[5] = f2b(v1.y);
    af.u[6] = f2b(v1.z); af.u[7] = f2b(v1.w);
    afr[k0] = af.v;
  }
  __syncthreads();

  f32x4 acc[8] = {};
#pragma unroll
  for (int k0 = 0; k0 < 4; ++k0) {
#pragma unroll
    for (int c = 0; c < 8; ++c) {
      bf16x8 bf = *(const bf16x8*)&Ws[(c * 16 + m) * LDW + k0 * 32 + quad * 8];
      acc[c] = __builtin_amdgcn_mfma_f32_16x16x32_bf16(afr[k0], bf, acc[c], 0, 0, 0);
    }
  }

  // C/D layout: col = lane&15 (within c-tile), row = quad*4 + r
  unsigned short* hp = hb + row0 * 128;
#pragma unroll
  for (int c = 0; c < 8; ++c)
#pragma unroll
    for (int r = 0; r < 4; ++r)
      hp[(quad * 4 + r) * 128 + c * 16 + m] = f2b(acc[c][r]);

  // fused g1/g2: per-row dot with a1/a2 from fp32 accumulators
  float a1v[8], a2v[8];
#pragma unroll
  for (int c = 0; c < 8; ++c) {
    a1v[c] = a[c * 16 + m];
    a2v[c] = a[128 + c * 16 + m];
  }
  float p1[4] = {}, p2[4] = {};
#pragma unroll
  for (int c = 0; c < 8; ++c)
#pragma unroll
    for (int r = 0; r < 4; ++r) {
      p1[r] = fmaf(acc[c][r], a1v[c], p1[r]);
      p2[r] = fmaf(acc[c][r], a2v[c], p2[r]);
    }
#pragma unroll
  for (int off = 1; off < 16; off <<= 1)
#pragma unroll
    for (int r = 0; r < 4; ++r) {
      p1[r] += __shfl_xor(p1[r], off, 64);
      p2[r] += __shfl_xor(p2[r], off, 64);
    }
  if (m == 0) {
    size_t rbase = row0 + quad * 4;
#pragma unroll
    for (int r = 0; r < 4; ++r) {
      g1[rbase + r] = p1[r];
      g2[rbase + r] = p2[r];
    }
  }
}

// ---- ELL scatter: one pass, replaces hist+scan+scatter --------------------
__global__ __launch_bounds__(256) void ell_scatter_kernel(
    const int* __restrict__ src, const int* __restrict__ dst,
    int* __restrict__ cursor, int* __restrict__ ell) {
  int e = blockIdx.x * 256 + threadIdx.x;
  if (e < NE) {
    int s = src[e];
    int d = dst[e];
    int slot = atomicAdd(&cursor[s], 1);
    if (slot < ELLW) ell[s * ELLW + slot] = d;   // overflow impossible; clamp for safety
  }
}

// ---------------- gather: lane-owns-2-cols, zero-reduce epilogue ------------
// Wave = (node i, batch b), b = bid&7 XCD-affine over batch-major hb.
// Lane l owns cols [2l, 2l+1]: per edge = 2 shfl + 1 dword load (256B/wave,
// coalesced) + 2-op bf16 unpack + 2 fma. Accumulator = 2 floats. Epilogue:
// only the rs 6-swizzle reduce; ELU via hardware v_exp; coalesced f32x2 store.
__global__ __launch_bounds__(256) void gather_kernel(
    const unsigned short* __restrict__ hb, const float* __restrict__ g1,
    const float* __restrict__ g2, const int* __restrict__ degs,
    const int* __restrict__ ell, float* __restrict__ out) {
  const int bid = blockIdx.x;
  const int b = bid & 7;                     // XCD-affine batch
  const int wv = threadIdx.x >> 6;
  const int i = (bid >> 3) * 4 + wv;         // node for this wave
  const int lane = threadIdx.x & 63;
  const int deg = min(degs[i], ELLW);        // >= 1 (src contains arange(N))
  const int base = i * ELLW;
  const float g1i = g1[(size_t)b * NN + i];
  const float* g2b = g2 + (size_t)b * NN;
  // lane's dword (cols 2l, 2l+1) within any h-row of batch b
  const char* hrow = (const char*)(hb + (size_t)b * NN * 128) + lane * 4;

  float accLo = 0.f, accHi = 0.f;
  float rs = 0.f;
  for (int c0 = 0; c0 < deg; c0 += 64) {
    const int cnt = min(64, deg - c0);
    const int li = lane < cnt ? lane : cnt - 1;
    const int dvec = ell[base + c0 + li];    // coalesced chunk of dst indices
    float w = 0.f;
    if (lane < cnt) {
      float sv = g1i + g2b[dvec];            // L2-resident 4B gather
      float sc = fmaxf(sv, LRALPHA * sv);
      w = __expf(-sc);
    }
    rs += w;
    const int cr = (cnt + 3) & ~3;           // pad: lanes >= cnt carry w=0
    for (int j = 0; j < cr; j += 4) {
#pragma unroll
      for (int jj = 0; jj < 4; ++jj) {
        float wj = __shfl(w, j + jj, 64);
        int dj = __shfl(dvec, j + jj, 64);
        unsigned int u = *(const unsigned int*)(hrow + ((size_t)dj << 8));
        accLo = fmaf(wj, __uint_as_float(u << 16), accLo);
        accHi = fmaf(wj, __uint_as_float(u & 0xFFFF0000u), accHi);
      }
    }
  }
#pragma unroll
  for (int off = 1; off < 64; off <<= 1) rs += __shfl_xor(rs, off, 64);

  const float inv = 1.f / rs;
  float v0 = accLo * inv;
  float v1 = accHi * inv;
  float o0 = v0 > 0.f ? v0 : __expf(v0) - 1.f;   // elu (alpha=1)
  float o1 = v1 > 0.f ? v1 : __expf(v1) - 1.f;
  float2* op = (float2*)(out + ((size_t)b * NN + i) * 128 + lane * 2);
  *op = make_float2(o0, o1);
}

extern "C" void kernel_launch(void* const* d_in, const int* in_sizes, int n_in,
                              void* d_out, int out_size, void* d_ws, size_t ws_size,
                              hipStream_t stream) {
  const float* x = (const float*)d_in[0];
  const float* W = (const float*)d_in[1];
  const float* a = (const float*)d_in[2];
  const int* edge = (const int*)d_in[3];
  const int* src = edge;
  const int* dst = edge + NE;
  float* out = (float*)d_out;

  // workspace layout (~50 MB)
  char* p = (char*)d_ws;
  unsigned short* hb = (unsigned short*)p;  p += (size_t)ROWS * 128 * 2;   // 40.96 MB
  float* g1 = (float*)p;                    p += (size_t)ROWS * 4;
  float* g2 = (float*)p;                    p += (size_t)ROWS * 4;
  int* cursor = (int*)p;                    p += (size_t)NN * 4;
  int* ell = (int*)p;                       p += (size_t)NN * ELLW * 4;   // 7.68 MB
  unsigned short* Wb = (unsigned short*)p;  p += (size_t)FI * FO * 2;

  wt_kernel<<<80, 256, 0, stream>>>(W, Wb, cursor);  // also zeroes cursor
  gemm_kernel<<<ROWS / 64, 256, 0, stream>>>(x, Wb, a, hb, g1, g2);
  ell_scatter_kernel<<<(NE + 255) / 256, 256, 0, stream>>>(src, dst, cursor, ell);
  gather_kernel<<<(NN / 4) * NB, 256, 0, stream>>>(hb, g1, g2, cursor, ell, out);
}